// Round 19
// baseline (134.315 us; speedup 1.0000x reference)
//
#include <hip/hip_runtime.h>
#include <hip/hip_bf16.h>
#include <math.h>

#define BB 4
#define SS 1024
#define DD 512
#define HH 16
#define HD 32
#define NTOK (BB * SS)             // 4096
#define NELEM ((size_t)NTOK * DD)  // 2M elements per [B,S,D]
#define SCALE 0.17677669529663687f // 1/sqrt(32)
#define SCLOG2E 0.25505526082484745f // SCALE * log2(e)

typedef __attribute__((ext_vector_type(8))) __bf16 bf16x8;
typedef __attribute__((ext_vector_type(4))) __bf16 bf16x4;
typedef __attribute__((ext_vector_type(4))) float f32x4;
typedef __attribute__((ext_vector_type(4))) unsigned short us4;
typedef __attribute__((ext_vector_type(4))) short s16x4;

__device__ __forceinline__ void gload16(const void* g, void* l) {
    __builtin_amdgcn_global_load_lds(
        (const __attribute__((address_space(1))) void*)g,
        (__attribute__((address_space(3))) void*)l, 16, 0, 0);
}

// ---------------------------------------------------------------------------
// Kernel 1: LayerNorm  x[4096,512] f32 -> xn bf16
// ---------------------------------------------------------------------------
__global__ __launch_bounds__(256) void ln_kernel(const float* __restrict__ x,
                                                 const float* __restrict__ g,
                                                 const float* __restrict__ bta,
                                                 __bf16* __restrict__ xn) {
    int row = blockIdx.x;
    int tid = threadIdx.x;
    const float* xr = x + (size_t)row * DD;
    float2 v = *reinterpret_cast<const float2*>(&xr[tid * 2]);
    float s1 = v.x + v.y;
    float s2 = v.x * v.x + v.y * v.y;
    for (int off = 32; off > 0; off >>= 1) {
        s1 += __shfl_down(s1, off);
        s2 += __shfl_down(s2, off);
    }
    __shared__ float r1[4], r2[4];
    int w = tid >> 6;
    if ((tid & 63) == 0) { r1[w] = s1; r2[w] = s2; }
    __syncthreads();
    s1 = r1[0] + r1[1] + r1[2] + r1[3];
    s2 = r2[0] + r2[1] + r2[2] + r2[3];
    float mu = s1 * (1.0f / DD);
    float var = s2 * (1.0f / DD) - mu * mu;
    float rstd = rsqrtf(var + 1e-5f);
    float2 gg = *reinterpret_cast<const float2*>(&g[tid * 2]);
    float2 bb = *reinterpret_cast<const float2*>(&bta[tid * 2]);
    __bf16* xp = xn + (size_t)row * DD + tid * 2;
    xp[0] = (__bf16)((v.x - mu) * rstd * gg.x + bb.x);
    xp[1] = (__bf16)((v.y - mu) * rstd * gg.y + bb.y);
}

// ---------------------------------------------------------------------------
// Kernel 2: weight prep — Wt[z][n][k] = bf16(W_z[k][n]), z = 0..6
// ---------------------------------------------------------------------------
struct W7 { const float* p[7]; };

__global__ __launch_bounds__(256) void wprep(W7 wp, __bf16* __restrict__ Wt) {
    int z = blockIdx.z;
    int kt = blockIdx.x, nt = blockIdx.y;
    const float* W = wp.p[z];
    __shared__ float lds[32][33];
    int tid = threadIdx.x;
    int r = tid >> 3, c4 = (tid & 7) * 4;
    float4 vv = *reinterpret_cast<const float4*>(W + (size_t)(kt * 32 + r) * DD + nt * 32 + c4);
    lds[r][c4 + 0] = vv.x; lds[r][c4 + 1] = vv.y;
    lds[r][c4 + 2] = vv.z; lds[r][c4 + 3] = vv.w;
    __syncthreads();
    __bf16* o = Wt + (size_t)z * DD * DD + (size_t)(nt * 32 + r) * DD + kt * 32 + c4;
    o[0] = (__bf16)lds[c4 + 0][r];
    o[1] = (__bf16)lds[c4 + 1][r];
    o[2] = (__bf16)lds[c4 + 2][r];
    o[3] = (__bf16)lds[c4 + 3][r];
}

// ---------------------------------------------------------------------------
// Kernel 3: bf16 MFMA GEMM — round-14 pipeline + XCD-locality swizzle
// (round-19): consecutive dispatch IDs round-robin XCDs, so map id&7 = xcd
// to 4 contiguous A-panels + whole W_z (~1MB working set per XCD L2).
// Tile BM=128, BN=64, BK=64; dbuf 24KB pair; counted vmcnt(6).
// mode: 0 = f32 (+resid), 1 = sigmoid->bf16, 2 = bf16, 3 = bf16*SCLOG2E (q)
// ---------------------------------------------------------------------------
struct GemmCfg { const float* bias[6]; void* out[6]; int mode[6]; };

__global__ __launch_bounds__(256) void mfma_gemm(const __bf16* __restrict__ A,
                                                 const __bf16* __restrict__ Wt0,
                                                 GemmCfg cfg,
                                                 const float* __restrict__ resid) {
    __shared__ __align__(16) char smem[49152];
    int z = blockIdx.z;
    const char* Ab8 = (const char*)A;
    const char* Bb8 = (const char*)(Wt0 + (size_t)z * DD * DD);
    int tid = threadIdx.x;
    int l = tid & 63, wid = tid >> 6;
    int lr = l & 15, lg = l >> 4;
    int wm = wid >> 1, wn = wid & 1;
    // XCD-locality swizzle: id&7 ~ XCD; each XCD gets m-panel group
    int id = blockIdx.y * 32 + blockIdx.x;      // 0..255 (x fastest in dispatch)
    int xcd = id & 7, loc = id >> 3;            // loc 0..31
    int bm = (xcd * 4 + (loc >> 3)) * 128;
    int bn = (loc & 7) * 64;

    f32x4 acc[4][2];
#pragma unroll
    for (int i = 0; i < 4; ++i)
#pragma unroll
        for (int j = 0; j < 2; ++j) acc[i][j] = (f32x4){0.f, 0.f, 0.f, 0.f};

    auto stage = [&](int k0, int bsel) {
        char* base = smem + bsel * 24576;
#pragma unroll
        for (int i = 0; i < 4; ++i) {
            int r = wid * 32 + i * 8 + (l >> 3);
            int cb = ((l & 7) * 16) ^ ((r & 7) << 4);
            gload16(Ab8 + (size_t)(bm + r) * 1024 + k0 * 2 + cb,
                    base + wid * 4096 + i * 1024);
        }
#pragma unroll
        for (int i = 0; i < 2; ++i) {
            int r = wid * 16 + i * 8 + (l >> 3);
            int cb = ((l & 7) * 16) ^ ((r & 7) << 4);
            gload16(Bb8 + (size_t)(bn + r) * 1024 + k0 * 2 + cb,
                    base + 16384 + wid * 2048 + i * 1024);
        }
    };

    stage(0, 0);
    for (int ks = 0; ks < 8; ++ks) {
        __builtin_amdgcn_s_barrier();
        if (ks < 7) {
            stage((ks + 1) * 64, (ks + 1) & 1);
            asm volatile("s_waitcnt vmcnt(6)" ::: "memory");
        } else {
            asm volatile("s_waitcnt vmcnt(0)" ::: "memory");
        }
        __builtin_amdgcn_s_barrier();
        __builtin_amdgcn_sched_barrier(0);

        const char* cbase = smem + (ks & 1) * 24576;
#pragma unroll
        for (int kk = 0; kk < 2; ++kk) {
            bf16x8 af[4], wf[2];
#pragma unroll
            for (int mi = 0; mi < 4; ++mi) {
                int m = wm * 64 + mi * 16 + lr;
                af[mi] = *reinterpret_cast<const bf16x8*>(
                    cbase + m * 128 + ((kk * 64 + lg * 16) ^ ((m & 7) << 4)));
            }
#pragma unroll
            for (int ni = 0; ni < 2; ++ni) {
                int n = wn * 32 + ni * 16 + lr;
                wf[ni] = *reinterpret_cast<const bf16x8*>(
                    cbase + 16384 + n * 128 + ((kk * 64 + lg * 16) ^ ((n & 7) << 4)));
            }
            __builtin_amdgcn_s_setprio(1);
#pragma unroll
            for (int mi = 0; mi < 4; ++mi)
#pragma unroll
                for (int ni = 0; ni < 2; ++ni)
                    acc[mi][ni] = __builtin_amdgcn_mfma_f32_16x16x32_bf16(af[mi], wf[ni], acc[mi][ni], 0, 0, 0);
            __builtin_amdgcn_s_setprio(0);
        }
    }

    int bmw = bm + wm * 64;
    int bnw = bn + wn * 32;
    int mode = cfg.mode[z];
    const float* bias = cfg.bias[z];
    float bv[2] = {bias[bnw + lr], bias[bnw + 16 + lr]};
#pragma unroll
    for (int mi = 0; mi < 4; ++mi) {
#pragma unroll
        for (int ni = 0; ni < 2; ++ni) {
#pragma unroll
            for (int r = 0; r < 4; ++r) {
                int row = bmw + mi * 16 + lg * 4 + r;
                int col = bnw + ni * 16 + lr;
                float val = acc[mi][ni][r] + bv[ni];
                if (mode == 0) {
                    if (resid) val += resid[(size_t)row * DD + col];
                    ((float*)cfg.out[z])[(size_t)row * DD + col] = val;
                } else if (mode == 1) {
                    val = 1.0f / (1.0f + expf(-val));
                    ((__bf16*)cfg.out[z])[(size_t)row * DD + col] = (__bf16)val;
                } else if (mode == 3) {
                    ((__bf16*)cfg.out[z])[(size_t)row * DD + col] = (__bf16)(val * SCLOG2E);
                } else {
                    ((__bf16*)cfg.out[z])[(size_t)row * DD + col] = (__bf16)val;
                }
            }
        }
    }
}

// ---------------------------------------------------------------------------
// Kernel 4a/4b: anchor softmax over sequence axis (per b, channel)
// ---------------------------------------------------------------------------
__global__ __launch_bounds__(256) void anchor_partial(const __bf16* __restrict__ fa,
                                                      float* __restrict__ pmax,
                                                      float* __restrict__ psum) {
    int tx = threadIdx.x;
    int ty = threadIdx.y;
    int c = blockIdx.x * 64 + tx;
    int b = blockIdx.y;
    int sc = blockIdx.z;
    const __bf16* base = fa + ((size_t)(b * SS + sc * 256)) * DD + c;
    float m = -1e30f;
    for (int i = ty; i < 256; i += 4) m = fmaxf(m, (float)base[(size_t)i * DD]);
    __shared__ float red[4][64];
    red[ty][tx] = m;
    __syncthreads();
    float cm = fmaxf(fmaxf(red[0][tx], red[1][tx]), fmaxf(red[2][tx], red[3][tx]));
    float s = 0.f;
    for (int i = ty; i < 256; i += 4) s += expf((float)base[(size_t)i * DD] - cm);
    __syncthreads();
    red[ty][tx] = s;
    __syncthreads();
    if (ty == 0) {
        float tot = red[0][tx] + red[1][tx] + red[2][tx] + red[3][tx];
        int o = (b * 4 + sc) * DD + c;
        pmax[o] = cm;
        psum[o] = tot;
    }
}

__global__ __launch_bounds__(256) void anchor_merge(const float* __restrict__ pmax,
                                                    const float* __restrict__ psum,
                                                    float2* __restrict__ smscale) {
    int idx = blockIdx.x * 256 + threadIdx.x;
    int b = idx >> 9;
    int c = idx & 511;
    float M = -1e30f;
#pragma unroll
    for (int j = 0; j < 4; ++j) M = fmaxf(M, pmax[(b * 4 + j) * DD + c]);
    float Z = 0.f;
#pragma unroll
    for (int j = 0; j < 4; ++j) Z += psum[(b * 4 + j) * DD + c] * expf(pmax[(b * 4 + j) * DD + c] - M);
    smscale[idx] = make_float2(M, 1.0f / Z);
}

// Kernel 4c: kw = k * exp(fa - M) * invZ  (vectorized bf16x8)
__global__ __launch_bounds__(256) void kweight(const __bf16* __restrict__ fa,
                                               const __bf16* __restrict__ kin,
                                               const float2* __restrict__ sm,
                                               __bf16* __restrict__ kw) {
    size_t f = ((size_t)blockIdx.x * 256 + threadIdx.x) * 8;
    int b = (int)(f >> 19);
    int c = (int)(f & 511);
    bf16x8 fv = *reinterpret_cast<const bf16x8*>(fa + f);
    bf16x8 kv = *reinterpret_cast<const bf16x8*>(kin + f);
    const float2* smb = sm + b * DD + c;
    bf16x8 o;
#pragma unroll
    for (int j = 0; j < 8; ++j) {
        float2 s = smb[j];
        o[j] = (__bf16)((float)kv[j] * expf((float)fv[j] - s.x) * s.y);
    }
    *reinterpret_cast<bf16x8*>(kw + f) = o;
}

// ---------------------------------------------------------------------------
// Kernel 5: V transpose into TILED layout:
//   vt2[b][t/8][drow=h*32+d (512)][t%8]   (8KB per (b,t/8) slice)
// ---------------------------------------------------------------------------
__global__ __launch_bounds__(256) void vtrans(const __bf16* __restrict__ v,
                                              __bf16* __restrict__ vt) {
    int t0 = blockIdx.x * 32;
    int h = blockIdx.y;
    int b = blockIdx.z;
    __shared__ unsigned short lds[32][33];
    int tid = threadIdx.x;
    int r = tid >> 3, c4 = (tid & 7) * 4;
    const unsigned short* vp = (const unsigned short*)v + ((size_t)(b * SS + t0 + r)) * DD + h * 32 + c4;
    us4 val = *reinterpret_cast<const us4*>(vp);
    lds[r][c4 + 0] = val[0]; lds[r][c4 + 1] = val[1];
    lds[r][c4 + 2] = val[2]; lds[r][c4 + 3] = val[3];
    __syncthreads();
    us4 o;
    o[0] = lds[c4 + 0][r]; o[1] = lds[c4 + 1][r];
    o[2] = lds[c4 + 2][r]; o[3] = lds[c4 + 3][r];  // o[j] = v[t0+c4+j][h*32+r]
    unsigned short* op = (unsigned short*)vt +
        ((size_t)(b * 128 + ((t0 + c4) >> 3)) * 512 + h * 32 + r) * 8 + (c4 & 7);
    *reinterpret_cast<us4*>(op) = o;
}

// ---------------------------------------------------------------------------
// Kernel 6: MFMA attention, head-split + dbuf counted-vmcnt pipeline
// (round-18 proven) + XCD-locality swizzle (round-19): each XCD owns 2
// (b,tp) pairs -> per-XCD L2 working set ~2MB (q_b + kw/vt slices).
// ---------------------------------------------------------------------------
struct P4 { __bf16* p[4]; };

__global__ __launch_bounds__(512) void attn_mfma(const __bf16* __restrict__ q,
                                                 const __bf16* __restrict__ kw,
                                                 const __bf16* __restrict__ vt,
                                                 P4 ps) {
    __shared__ __align__(16) char smem[65536];
    // XCD-locality swizzle over the 512-block grid (x fastest in dispatch)
    int id = blockIdx.x + 32 * (blockIdx.y + 4 * blockIdx.z);
    int xcd = id & 7, loc = id >> 3;            // loc 0..63
    int pair = 2 * xcd + (loc >> 5);            // 0..15 = b*4+tp
    int sgq = loc & 31;
    int b = pair >> 2;
    int tp = pair & 3;
    int tid = threadIdx.x;
    int wid = tid >> 6;       // 0..7
    int lane = tid & 63;
    int lg = lane >> 4;
    int lr = lane & 15;
    int sgrp = wid & 1;       // s-group within block
    int hq = wid >> 1;        // head quarter 0..3
    int hbase = hq * 4;
    int s0 = (sgq * 2 + sgrp) * 16;

    const __bf16* qbase = q + ((size_t)(b * SS + s0 + lr)) * DD + lg * 8;
    const char* kwb8 = (const char*)kw + (size_t)b * SS * DD * 2;
    const char* vtb8 = (const char*)vt + (size_t)b * 128 * 8192;

    bf16x8 qf[4];
#pragma unroll
    for (int hi = 0; hi < 4; ++hi)
        qf[hi] = *reinterpret_cast<const bf16x8*>(qbase + (hbase + hi) * 32);

    f32x4 acc[4][2];
#pragma unroll
    for (int hi = 0; hi < 4; ++hi) {
        acc[hi][0] = (f32x4){0.f, 0.f, 0.f, 0.f};
        acc[hi][1] = (f32x4){0.f, 0.f, 0.f, 0.f};
    }

    // per-wave: 2 kw loads FIRST, then 2 vt loads (counted-wait order)
    auto stage = [&](int tbase, int bsel) {
#pragma unroll
        for (int i = 0; i < 2; ++i) {
            int row = wid + i * 8;
            int colb = (lane * 16) ^ ((row & 15) << 4);
            gload16(kwb8 + (size_t)(tbase + row) * 1024 + colb,
                    smem + bsel * 16384 + row * 1024);
        }
#pragma unroll
        for (int i = 0; i < 2; ++i) {
            int blkid = wid + i * 8;
            gload16(vtb8 + (size_t)((tbase >> 3) + (blkid >> 3)) * 8192 + (blkid & 7) * 1024 + lane * 16,
                    smem + 32768 + bsel * 16384 + blkid * 1024);
        }
    };

    int tbase0 = tp * 256;
    stage(tbase0, 0);

    for (int tc = 0; tc < 256; tc += 16) {
        int cur = (tc >> 4) & 1;
        char* kwbuf = smem + cur * 16384;
        char* vtbuf = smem + 32768 + cur * 16384;
        char* xch = kwbuf + sgrp * 4096;   // aliases kw rows 0..7 (free after QK)

        asm volatile("s_waitcnt vmcnt(2)" ::: "memory");
        __builtin_amdgcn_s_barrier();
        __builtin_amdgcn_sched_barrier(0);

        // ---- QK: own 4 heads; t = tbase + 4*lg + r, row = lr (identity)
        f32x4 sc[4];
        bf16x8 ka[4];
#pragma unroll
        for (int hi = 0; hi < 4; ++hi)
            ka[hi] = *reinterpret_cast<const bf16x8*>(
                kwbuf + lr * 1024 + ((((hbase + hi) * 64) + lg * 16) ^ (lr << 4)));
        __builtin_amdgcn_s_setprio(1);
#pragma unroll
        for (int hi = 0; hi < 4; ++hi) {
            f32x4 z = (f32x4){0.f, 0.f, 0.f, 0.f};
            sc[hi] = __builtin_amdgcn_mfma_f32_16x16x32_bf16(ka[hi], qf[hi], z, 0, 0, 0);
        }
        __builtin_amdgcn_s_setprio(0);

        __builtin_amdgcn_s_barrier();
        __builtin_amdgcn_sched_barrier(0);

        // ---- softmax: local exp + partial sum; overlap next-chunk stage
#pragma unroll
        for (int hi = 0; hi < 4; ++hi)
#pragma unroll
            for (int r = 0; r < 4; ++r) sc[hi][r] = exp2f(sc[hi][r]);
        f32x4 zsp = sc[0] + sc[1] + sc[2] + sc[3];
        *reinterpret_cast<f32x4*>(xch + hq * 1024 + lane * 16) = zsp;
        if (tc + 16 < 256) stage(tbase0 + tc + 16, cur ^ 1);
        asm volatile("s_waitcnt lgkmcnt(0)" ::: "memory");
        __builtin_amdgcn_s_barrier();
        __builtin_amdgcn_sched_barrier(0);

        f32x4 zt = zsp;
#pragma unroll
        for (int p = 0; p < 4; ++p)
            if (p != hq) zt += *reinterpret_cast<const f32x4*>(xch + p * 1024 + lane * 16);
        float inv[4];
#pragma unroll
        for (int r = 0; r < 4; ++r) inv[r] = __builtin_amdgcn_rcpf(zt[r]);
        bf16x4 pA[4];
#pragma unroll
        for (int hi = 0; hi < 4; ++hi)
#pragma unroll
            for (int r = 0; r < 4; ++r) pA[hi][r] = (__bf16)(sc[hi][r] * inv[r]);

        if (tc + 16 < 256) {
            asm volatile("s_waitcnt vmcnt(4)" ::: "memory");
        } else {
            asm volatile("s_waitcnt vmcnt(0)" ::: "memory");
        }
        __builtin_amdgcn_s_barrier();
        __builtin_amdgcn_sched_barrier(0);

        // ---- PV (K=16): vf = 4 consecutive t at tbase + 4*lg
        const char* vb = vtbuf + (lg >> 1) * 8192 + (lg & 1) * 8;
#pragma unroll
        for (int hi = 0; hi < 4; hi += 2) {
            s16x4 vf[4];
#pragma unroll
            for (int j = 0; j < 2; ++j) {
                int h = hbase + hi + j;
                vf[2 * j + 0] = *reinterpret_cast<const s16x4*>(vb + (h * 32 + lr) * 16);
                vf[2 * j + 1] = *reinterpret_cast<const s16x4*>(vb + (h * 32 + 16 + lr) * 16);
            }
            __builtin_amdgcn_s_setprio(1);
#pragma unroll
            for (int j = 0; j < 2; ++j) {
                s16x4 pa = __builtin_bit_cast(s16x4, pA[hi + j]);
                acc[hi + j][0] = __builtin_amdgcn_mfma_f32_16x16x16bf16_1k(pa, vf[2 * j + 0], acc[hi + j][0], 0, 0, 0);
                acc[hi + j][1] = __builtin_amdgcn_mfma_f32_16x16x16bf16_1k(pa, vf[2 * j + 1], acc[hi + j][1], 0, 0, 0);
            }
            __builtin_amdgcn_s_setprio(0);
        }
        // next iter's top vmcnt(2)+barrier protects buffer reuse
    }

    __bf16* pb = ps.p[tp] + ((size_t)(b * SS + s0)) * DD;
#pragma unroll
    for (int hi = 0; hi < 4; ++hi)
#pragma unroll
        for (int dh = 0; dh < 2; ++dh)
#pragma unroll
            for (int r = 0; r < 4; ++r)
                pb[(size_t)(lg * 4 + r) * DD + (hbase + hi) * 32 + dh * 16 + lr] = (__bf16)acc[hi][dh][r];
}

// ---------------------------------------------------------------------------
// Kernel 7: combine  comb = (sum of 4 partials)*mg + hf  -> bf16
// ---------------------------------------------------------------------------
struct P4c { const __bf16* p[4]; };

__global__ __launch_bounds__(256) void combine_kernel(P4c ps,
                                                      const __bf16* __restrict__ mg,
                                                      const __bf16* __restrict__ hf,
                                                      __bf16* __restrict__ comb) {
    size_t f = ((size_t)blockIdx.x * 256 + threadIdx.x) * 8;
    float accv[8] = {0.f, 0.f, 0.f, 0.f, 0.f, 0.f, 0.f, 0.f};
#pragma unroll
    for (int i = 0; i < 4; ++i) {
        bf16x8 v = *reinterpret_cast<const bf16x8*>(ps.p[i] + f);
#pragma unroll
        for (int j = 0; j < 8; ++j) accv[j] += (float)v[j];
    }
    bf16x8 m = *reinterpret_cast<const bf16x8*>(mg + f);
    bf16x8 hh = *reinterpret_cast<const bf16x8*>(hf + f);
    bf16x8 o;
#pragma unroll
    for (int j = 0; j < 8; ++j) o[j] = (__bf16)(accv[j] * (float)m[j] + (float)hh[j]);
    *reinterpret_cast<bf16x8*>(comb + f) = o;
}

// ---------------------------------------------------------------------------
extern "C" void kernel_launch(void* const* d_in, const int* in_sizes, int n_in,
                              void* d_out, int out_size, void* d_ws, size_t ws_size,
                              hipStream_t stream) {
    const float* x    = (const float*)d_in[0];
    const float* ln_g = (const float*)d_in[1];
    const float* ln_b = (const float*)d_in[2];
    const float* Wfa  = (const float*)d_in[3];  const float* bfa = (const float*)d_in[4];
    const float* Whp  = (const float*)d_in[5];  const float* bhp = (const float*)d_in[6];
    const float* Wmg  = (const float*)d_in[7];  const float* bmg = (const float*)d_in[8];
    const float* Wq   = (const float*)d_in[9];  const float* bq  = (const float*)d_in[10];
    const float* Wk   = (const float*)d_in[11]; const float* bk  = (const float*)d_in[12];
    const float* Wv   = (const float*)d_in[13]; const float* bv  = (const float*)d_in[14];
    const float* Wo   = (const float*)d_in[15]; const float* bo  = (const float*)d_in[16];
    float* out = (float*)d_out;

    char* w8 = (char*)d_ws;
    // Memory map (MB offsets). Every [B,S,D] bf16 tensor is 4 MB.
    __bf16* Wt   = (__bf16*)(w8 + ((size_t) 0 << 20)); // 3.5 MB used
    __bf16* xn   = (__bf16*)(w8 + ((size_t) 4 << 20)); // [4,8)   dead after 6-gemm
    __bf16* fa   = (__bf16*)(w8 + ((size_t) 8 << 20)); // [8,12)  dead after kweight
    __bf16* hf   = (__bf16*)(w8 + ((size_t)12 << 20)); // [12,16)
    __bf16* mg   = (__bf16*)(w8 + ((size_t)16 << 20)); // [16,20)
    __bf16* q    = (__bf16*)(w8 + ((size_t)20 << 20)); // [20,24)
    __bf16* k    = (__bf16*)(w8 + ((size_t)24 << 20)); // [24,28) dead after kweight
    __bf16* v    = (__bf16*)(w8 + ((size_t)28 << 20)); // [28,32) dead after vtrans
    __bf16* kw   = (__bf16*)(w8 + ((size_t)32 << 20)); // [32,36)
    __bf16* vt   = (__bf16*)(w8 + ((size_t)36 << 20)); // [36,40)
    // 4 bf16 partials (4 MB each): reuse dead xn/fa/k/v
    P4 ps;
    ps.p[0] = (__bf16*)(w8 + ((size_t) 4 << 20));
    ps.p[1] = (__bf16*)(w8 + ((size_t) 8 << 20));
    ps.p[2] = (__bf16*)(w8 + ((size_t)24 << 20));
    ps.p[3] = (__bf16*)(w8 + ((size_t)28 << 20));
    __bf16* comb = (__bf16*)(w8 + ((size_t)56 << 20)); // [56,60)
    float* pmax  = (float*) (w8 + ((size_t)60 << 20)); // stats ~80 KB
    float* psum  = pmax + 16 * DD;
    float2* smsc = (float2*)(psum + 16 * DD);

    // 1. LayerNorm -> xn bf16
    ln_kernel<<<NTOK, 256, 0, stream>>>(x, ln_g, ln_b, xn);

    // 2. Weight transpose+cast
    W7 wp; wp.p[0]=Wfa; wp.p[1]=Whp; wp.p[2]=Wmg; wp.p[3]=Wq; wp.p[4]=Wk; wp.p[5]=Wv; wp.p[6]=Wo;
    wprep<<<dim3(16, 16, 7), 256, 0, stream>>>(wp, Wt);

    // 3. Fused 6-projection MFMA GEMM (128x64 dbuf + XCD swizzle)
    GemmCfg cfg;
    cfg.bias[0]=bfa; cfg.out[0]=fa; cfg.mode[0]=2;
    cfg.bias[1]=bhp; cfg.out[1]=hf; cfg.mode[1]=2;
    cfg.bias[2]=bmg; cfg.out[2]=mg; cfg.mode[2]=1;
    cfg.bias[3]=bq;  cfg.out[3]=q;  cfg.mode[3]=3;
    cfg.bias[4]=bk;  cfg.out[4]=k;  cfg.mode[4]=2;
    cfg.bias[5]=bv;  cfg.out[5]=v;  cfg.mode[5]=2;
    mfma_gemm<<<dim3(32, 8, 6), 256, 0, stream>>>(xn, Wt, cfg, nullptr);

    // 4. anchor softmax over sequence axis
    anchor_partial<<<dim3(8, 4, 4), dim3(64, 4), 0, stream>>>(fa, pmax, psum);
    anchor_merge<<<8, 256, 0, stream>>>(pmax, psum, smsc);
    kweight<<<1024, 256, 0, stream>>>(fa, k, smsc, kw);

    // 5. V transpose (tiled layout)
    vtrans<<<dim3(32, 16, 4), 256, 0, stream>>>(v, vt);

    // 6. MFMA attention -> 4 bf16 partials (pipelined + XCD swizzle)
    attn_mfma<<<dim3(32, 4, 4), 512, 0, stream>>>(q, kw, vt, ps);

    // 7. combine
    P4c pc;
    for (int i = 0; i < 4; ++i) pc.p[i] = ps.p[i];
    combine_kernel<<<1024, 256, 0, stream>>>(pc, mg, hf, comb);

    // 8. output projection + residual (128x64 dbuf + XCD swizzle)
    GemmCfg cfg2;
    for (int i = 0; i < 6; ++i) { cfg2.bias[i]=bo; cfg2.out[i]=out; cfg2.mode[i]=0; }
    mfma_gemm<<<dim3(32, 8, 1), 256, 0, stream>>>(comb, Wt + (size_t)6 * DD * DD, cfg2, x);
}

// Round 20
// 122.268 us; speedup vs baseline: 1.0985x; 1.0985x over previous
//
#include <hip/hip_runtime.h>
#include <hip/hip_bf16.h>
#include <math.h>

#define BB 4
#define SS 1024
#define DD 512
#define HH 16
#define HD 32
#define NTOK (BB * SS)             // 4096
#define NELEM ((size_t)NTOK * DD)  // 2M elements per [B,S,D]
#define SCALE 0.17677669529663687f // 1/sqrt(32)
#define SCLOG2E 0.25505526082484745f // SCALE * log2(e)

typedef __attribute__((ext_vector_type(8))) __bf16 bf16x8;
typedef __attribute__((ext_vector_type(4))) __bf16 bf16x4;
typedef __attribute__((ext_vector_type(4))) float f32x4;
typedef __attribute__((ext_vector_type(4))) unsigned short us4;
typedef __attribute__((ext_vector_type(4))) short s16x4;

__device__ __forceinline__ void gload16(const void* g, void* l) {
    __builtin_amdgcn_global_load_lds(
        (const __attribute__((address_space(1))) void*)g,
        (__attribute__((address_space(3))) void*)l, 16, 0, 0);
}

// ---------------------------------------------------------------------------
// Kernel 1: LayerNorm  x[4096,512] f32 -> xn bf16
// ---------------------------------------------------------------------------
__global__ __launch_bounds__(256) void ln_kernel(const float* __restrict__ x,
                                                 const float* __restrict__ g,
                                                 const float* __restrict__ bta,
                                                 __bf16* __restrict__ xn) {
    int row = blockIdx.x;
    int tid = threadIdx.x;
    const float* xr = x + (size_t)row * DD;
    float2 v = *reinterpret_cast<const float2*>(&xr[tid * 2]);
    float s1 = v.x + v.y;
    float s2 = v.x * v.x + v.y * v.y;
    for (int off = 32; off > 0; off >>= 1) {
        s1 += __shfl_down(s1, off);
        s2 += __shfl_down(s2, off);
    }
    __shared__ float r1[4], r2[4];
    int w = tid >> 6;
    if ((tid & 63) == 0) { r1[w] = s1; r2[w] = s2; }
    __syncthreads();
    s1 = r1[0] + r1[1] + r1[2] + r1[3];
    s2 = r2[0] + r2[1] + r2[2] + r2[3];
    float mu = s1 * (1.0f / DD);
    float var = s2 * (1.0f / DD) - mu * mu;
    float rstd = rsqrtf(var + 1e-5f);
    float2 gg = *reinterpret_cast<const float2*>(&g[tid * 2]);
    float2 bb = *reinterpret_cast<const float2*>(&bta[tid * 2]);
    __bf16* xp = xn + (size_t)row * DD + tid * 2;
    xp[0] = (__bf16)((v.x - mu) * rstd * gg.x + bb.x);
    xp[1] = (__bf16)((v.y - mu) * rstd * gg.y + bb.y);
}

// ---------------------------------------------------------------------------
// Kernel 2: weight prep — Wt[z][n][k] = bf16(W_z[k][n]), z = 0..6
// ---------------------------------------------------------------------------
struct W7 { const float* p[7]; };

__global__ __launch_bounds__(256) void wprep(W7 wp, __bf16* __restrict__ Wt) {
    int z = blockIdx.z;
    int kt = blockIdx.x, nt = blockIdx.y;
    const float* W = wp.p[z];
    __shared__ float lds[32][33];
    int tid = threadIdx.x;
    int r = tid >> 3, c4 = (tid & 7) * 4;
    float4 vv = *reinterpret_cast<const float4*>(W + (size_t)(kt * 32 + r) * DD + nt * 32 + c4);
    lds[r][c4 + 0] = vv.x; lds[r][c4 + 1] = vv.y;
    lds[r][c4 + 2] = vv.z; lds[r][c4 + 3] = vv.w;
    __syncthreads();
    __bf16* o = Wt + (size_t)z * DD * DD + (size_t)(nt * 32 + r) * DD + kt * 32 + c4;
    o[0] = (__bf16)lds[c4 + 0][r];
    o[1] = (__bf16)lds[c4 + 1][r];
    o[2] = (__bf16)lds[c4 + 2][r];
    o[3] = (__bf16)lds[c4 + 3][r];
}

// ---------------------------------------------------------------------------
// GemmCfg: per-slot bias/out/mode (slots 0..5)
// mode: 0 = f32 (+resid), 1 = sigmoid->bf16, 2 = bf16, 3 = bf16*SCLOG2E (q)
// ---------------------------------------------------------------------------
struct GemmCfg { const float* bias[6]; void* out[6]; int mode[6]; };

// ---------------------------------------------------------------------------
// Kernel 3a: FUSED 3-projection MFMA GEMM (round-20). The same A-tile feeds
// all projections: stage A ONCE + 3 B-tiles per K-step. Per-K-step compute
// triples (48 MFMA ~ 700cy) -> 1-deep prefetch now covers ~600cy L2 latency;
// A-staging traffic drops 3x. grid (32, 8, 2): z-half covers slots 3*zh..+2.
// Tile BM=128, BN=64, BK=64; dbuf 40KB pair (80KB -> 2 blocks/CU);
// counted vmcnt(10). acc 96 VGPR (3 x 4x2 f32x4).
// ---------------------------------------------------------------------------
__global__ __launch_bounds__(256) void mfma_gemm3(const __bf16* __restrict__ A,
                                                  const __bf16* __restrict__ Wt0,
                                                  GemmCfg cfg) {
    __shared__ __align__(16) char smem[81920]; // buf i @ i*40960: A 16K, B0..2 @+16384+z*8192
    int zh = blockIdx.z;                       // 0..1
    const char* Ab8 = (const char*)A;
    int tid = threadIdx.x;
    int l = tid & 63, wid = tid >> 6;
    int lr = l & 15, lg = l >> 4;
    int wm = wid >> 1, wn = wid & 1;
    int bm = blockIdx.x * 128;
    int bn = blockIdx.y * 64;
    const char* Bb8[3];
#pragma unroll
    for (int z = 0; z < 3; ++z)
        Bb8[z] = (const char*)(Wt0 + (size_t)(zh * 3 + z) * DD * DD);

    f32x4 acc[3][4][2];
#pragma unroll
    for (int z = 0; z < 3; ++z)
#pragma unroll
        for (int i = 0; i < 4; ++i)
#pragma unroll
            for (int j = 0; j < 2; ++j) acc[z][i][j] = (f32x4){0.f, 0.f, 0.f, 0.f};

    auto stage = [&](int k0, int bsel) {
        char* base = smem + bsel * 40960;
#pragma unroll
        for (int i = 0; i < 4; ++i) {
            int r = wid * 32 + i * 8 + (l >> 3);
            int cb = ((l & 7) * 16) ^ ((r & 7) << 4);
            gload16(Ab8 + (size_t)(bm + r) * 1024 + k0 * 2 + cb,
                    base + wid * 4096 + i * 1024);
        }
#pragma unroll
        for (int z = 0; z < 3; ++z)
#pragma unroll
            for (int i = 0; i < 2; ++i) {
                int r = wid * 16 + i * 8 + (l >> 3);
                int cb = ((l & 7) * 16) ^ ((r & 7) << 4);
                gload16(Bb8[z] + (size_t)(bn + r) * 1024 + k0 * 2 + cb,
                        base + 16384 + z * 8192 + wid * 2048 + i * 1024);
            }
    };

    stage(0, 0);
    for (int ks = 0; ks < 8; ++ks) {
        __builtin_amdgcn_s_barrier();      // buf[(ks+1)&1] free (consumed ks-1)
        if (ks < 7) {
            stage((ks + 1) * 64, (ks + 1) & 1);
            asm volatile("s_waitcnt vmcnt(10)" ::: "memory"); // stage(ks) done
        } else {
            asm volatile("s_waitcnt vmcnt(0)" ::: "memory");
        }
        __builtin_amdgcn_s_barrier();      // stage(ks) visible to all waves
        __builtin_amdgcn_sched_barrier(0);

        const char* cbase = smem + (ks & 1) * 40960;
#pragma unroll
        for (int kk = 0; kk < 2; ++kk) {
            bf16x8 af[4];
#pragma unroll
            for (int mi = 0; mi < 4; ++mi) {
                int m = wm * 64 + mi * 16 + lr;
                af[mi] = *reinterpret_cast<const bf16x8*>(
                    cbase + m * 128 + ((kk * 64 + lg * 16) ^ ((m & 7) << 4)));
            }
#pragma unroll
            for (int z = 0; z < 3; ++z) {
                bf16x8 wf[2];
#pragma unroll
                for (int ni = 0; ni < 2; ++ni) {
                    int n = wn * 32 + ni * 16 + lr;
                    wf[ni] = *reinterpret_cast<const bf16x8*>(
                        cbase + 16384 + z * 8192 + n * 128 + ((kk * 64 + lg * 16) ^ ((n & 7) << 4)));
                }
                __builtin_amdgcn_s_setprio(1);
#pragma unroll
                for (int mi = 0; mi < 4; ++mi)
#pragma unroll
                    for (int ni = 0; ni < 2; ++ni)
                        acc[z][mi][ni] = __builtin_amdgcn_mfma_f32_16x16x32_bf16(af[mi], wf[ni], acc[z][mi][ni], 0, 0, 0);
                __builtin_amdgcn_s_setprio(0);
            }
        }
    }

    int bmw = bm + wm * 64;
    int bnw = bn + wn * 32;
#pragma unroll
    for (int z = 0; z < 3; ++z) {
        int slot = zh * 3 + z;
        int mode = cfg.mode[slot];
        const float* bias = cfg.bias[slot];
        float bv[2] = {bias[bnw + lr], bias[bnw + 16 + lr]};
#pragma unroll
        for (int mi = 0; mi < 4; ++mi) {
#pragma unroll
            for (int ni = 0; ni < 2; ++ni) {
#pragma unroll
                for (int r = 0; r < 4; ++r) {
                    int row = bmw + mi * 16 + lg * 4 + r;
                    int col = bnw + ni * 16 + lr;
                    float val = acc[z][mi][ni][r] + bv[ni];
                    if (mode == 1) {
                        val = 1.0f / (1.0f + expf(-val));
                        ((__bf16*)cfg.out[slot])[(size_t)row * DD + col] = (__bf16)val;
                    } else if (mode == 3) {
                        ((__bf16*)cfg.out[slot])[(size_t)row * DD + col] = (__bf16)(val * SCLOG2E);
                    } else {
                        ((__bf16*)cfg.out[slot])[(size_t)row * DD + col] = (__bf16)val;
                    }
                }
            }
        }
    }
}

// ---------------------------------------------------------------------------
// Kernel 3b: single-output bf16 MFMA GEMM (round-14/18 proven) — used for
// the output projection. Tile BM=128 BN=64 BK=64; dbuf 24KB pair; vmcnt(6).
// ---------------------------------------------------------------------------
__global__ __launch_bounds__(256) void mfma_gemm(const __bf16* __restrict__ A,
                                                 const __bf16* __restrict__ Wt0,
                                                 GemmCfg cfg,
                                                 const float* __restrict__ resid) {
    __shared__ __align__(16) char smem[49152];
    int z = blockIdx.z;
    const char* Ab8 = (const char*)A;
    const char* Bb8 = (const char*)(Wt0 + (size_t)z * DD * DD);
    int tid = threadIdx.x;
    int l = tid & 63, wid = tid >> 6;
    int lr = l & 15, lg = l >> 4;
    int wm = wid >> 1, wn = wid & 1;
    int bm = blockIdx.x * 128;
    int bn = blockIdx.y * 64;

    f32x4 acc[4][2];
#pragma unroll
    for (int i = 0; i < 4; ++i)
#pragma unroll
        for (int j = 0; j < 2; ++j) acc[i][j] = (f32x4){0.f, 0.f, 0.f, 0.f};

    auto stage = [&](int k0, int bsel) {
        char* base = smem + bsel * 24576;
#pragma unroll
        for (int i = 0; i < 4; ++i) {
            int r = wid * 32 + i * 8 + (l >> 3);
            int cb = ((l & 7) * 16) ^ ((r & 7) << 4);
            gload16(Ab8 + (size_t)(bm + r) * 1024 + k0 * 2 + cb,
                    base + wid * 4096 + i * 1024);
        }
#pragma unroll
        for (int i = 0; i < 2; ++i) {
            int r = wid * 16 + i * 8 + (l >> 3);
            int cb = ((l & 7) * 16) ^ ((r & 7) << 4);
            gload16(Bb8 + (size_t)(bn + r) * 1024 + k0 * 2 + cb,
                    base + 16384 + wid * 2048 + i * 1024);
        }
    };

    stage(0, 0);
    for (int ks = 0; ks < 8; ++ks) {
        __builtin_amdgcn_s_barrier();
        if (ks < 7) {
            stage((ks + 1) * 64, (ks + 1) & 1);
            asm volatile("s_waitcnt vmcnt(6)" ::: "memory");
        } else {
            asm volatile("s_waitcnt vmcnt(0)" ::: "memory");
        }
        __builtin_amdgcn_s_barrier();
        __builtin_amdgcn_sched_barrier(0);

        const char* cbase = smem + (ks & 1) * 24576;
#pragma unroll
        for (int kk = 0; kk < 2; ++kk) {
            bf16x8 af[4], wf[2];
#pragma unroll
            for (int mi = 0; mi < 4; ++mi) {
                int m = wm * 64 + mi * 16 + lr;
                af[mi] = *reinterpret_cast<const bf16x8*>(
                    cbase + m * 128 + ((kk * 64 + lg * 16) ^ ((m & 7) << 4)));
            }
#pragma unroll
            for (int ni = 0; ni < 2; ++ni) {
                int n = wn * 32 + ni * 16 + lr;
                wf[ni] = *reinterpret_cast<const bf16x8*>(
                    cbase + 16384 + n * 128 + ((kk * 64 + lg * 16) ^ ((n & 7) << 4)));
            }
            __builtin_amdgcn_s_setprio(1);
#pragma unroll
            for (int mi = 0; mi < 4; ++mi)
#pragma unroll
                for (int ni = 0; ni < 2; ++ni)
                    acc[mi][ni] = __builtin_amdgcn_mfma_f32_16x16x32_bf16(af[mi], wf[ni], acc[mi][ni], 0, 0, 0);
            __builtin_amdgcn_s_setprio(0);
        }
    }

    int bmw = bm + wm * 64;
    int bnw = bn + wn * 32;
    int mode = cfg.mode[z];
    const float* bias = cfg.bias[z];
    float bv[2] = {bias[bnw + lr], bias[bnw + 16 + lr]};
#pragma unroll
    for (int mi = 0; mi < 4; ++mi) {
#pragma unroll
        for (int ni = 0; ni < 2; ++ni) {
#pragma unroll
            for (int r = 0; r < 4; ++r) {
                int row = bmw + mi * 16 + lg * 4 + r;
                int col = bnw + ni * 16 + lr;
                float val = acc[mi][ni][r] + bv[ni];
                if (mode == 0) {
                    if (resid) val += resid[(size_t)row * DD + col];
                    ((float*)cfg.out[z])[(size_t)row * DD + col] = val;
                } else {
                    ((__bf16*)cfg.out[z])[(size_t)row * DD + col] = (__bf16)val;
                }
            }
        }
    }
}

// ---------------------------------------------------------------------------
// Kernel 4a/4b: anchor softmax over sequence axis (per b, channel)
// ---------------------------------------------------------------------------
__global__ __launch_bounds__(256) void anchor_partial(const __bf16* __restrict__ fa,
                                                      float* __restrict__ pmax,
                                                      float* __restrict__ psum) {
    int tx = threadIdx.x;
    int ty = threadIdx.y;
    int c = blockIdx.x * 64 + tx;
    int b = blockIdx.y;
    int sc = blockIdx.z;
    const __bf16* base = fa + ((size_t)(b * SS + sc * 256)) * DD + c;
    float m = -1e30f;
    for (int i = ty; i < 256; i += 4) m = fmaxf(m, (float)base[(size_t)i * DD]);
    __shared__ float red[4][64];
    red[ty][tx] = m;
    __syncthreads();
    float cm = fmaxf(fmaxf(red[0][tx], red[1][tx]), fmaxf(red[2][tx], red[3][tx]));
    float s = 0.f;
    for (int i = ty; i < 256; i += 4) s += expf((float)base[(size_t)i * DD] - cm);
    __syncthreads();
    red[ty][tx] = s;
    __syncthreads();
    if (ty == 0) {
        float tot = red[0][tx] + red[1][tx] + red[2][tx] + red[3][tx];
        int o = (b * 4 + sc) * DD + c;
        pmax[o] = cm;
        psum[o] = tot;
    }
}

__global__ __launch_bounds__(256) void anchor_merge(const float* __restrict__ pmax,
                                                    const float* __restrict__ psum,
                                                    float2* __restrict__ smscale) {
    int idx = blockIdx.x * 256 + threadIdx.x;
    int b = idx >> 9;
    int c = idx & 511;
    float M = -1e30f;
#pragma unroll
    for (int j = 0; j < 4; ++j) M = fmaxf(M, pmax[(b * 4 + j) * DD + c]);
    float Z = 0.f;
#pragma unroll
    for (int j = 0; j < 4; ++j) Z += psum[(b * 4 + j) * DD + c] * expf(pmax[(b * 4 + j) * DD + c] - M);
    smscale[idx] = make_float2(M, 1.0f / Z);
}

// Kernel 4c: kw = k * exp(fa - M) * invZ  (vectorized bf16x8)
__global__ __launch_bounds__(256) void kweight(const __bf16* __restrict__ fa,
                                               const __bf16* __restrict__ kin,
                                               const float2* __restrict__ sm,
                                               __bf16* __restrict__ kw) {
    size_t f = ((size_t)blockIdx.x * 256 + threadIdx.x) * 8;
    int b = (int)(f >> 19);
    int c = (int)(f & 511);
    bf16x8 fv = *reinterpret_cast<const bf16x8*>(fa + f);
    bf16x8 kv = *reinterpret_cast<const bf16x8*>(kin + f);
    const float2* smb = sm + b * DD + c;
    bf16x8 o;
#pragma unroll
    for (int j = 0; j < 8; ++j) {
        float2 s = smb[j];
        o[j] = (__bf16)((float)kv[j] * expf((float)fv[j] - s.x) * s.y);
    }
    *reinterpret_cast<bf16x8*>(kw + f) = o;
}

// ---------------------------------------------------------------------------
// Kernel 5: V transpose into TILED layout:
//   vt2[b][t/8][drow=h*32+d (512)][t%8]   (8KB per (b,t/8) slice)
// ---------------------------------------------------------------------------
__global__ __launch_bounds__(256) void vtrans(const __bf16* __restrict__ v,
                                              __bf16* __restrict__ vt) {
    int t0 = blockIdx.x * 32;
    int h = blockIdx.y;
    int b = blockIdx.z;
    __shared__ unsigned short lds[32][33];
    int tid = threadIdx.x;
    int r = tid >> 3, c4 = (tid & 7) * 4;
    const unsigned short* vp = (const unsigned short*)v + ((size_t)(b * SS + t0 + r)) * DD + h * 32 + c4;
    us4 val = *reinterpret_cast<const us4*>(vp);
    lds[r][c4 + 0] = val[0]; lds[r][c4 + 1] = val[1];
    lds[r][c4 + 2] = val[2]; lds[r][c4 + 3] = val[3];
    __syncthreads();
    us4 o;
    o[0] = lds[c4 + 0][r]; o[1] = lds[c4 + 1][r];
    o[2] = lds[c4 + 2][r]; o[3] = lds[c4 + 3][r];  // o[j] = v[t0+c4+j][h*32+r]
    unsigned short* op = (unsigned short*)vt +
        ((size_t)(b * 128 + ((t0 + c4) >> 3)) * 512 + h * 32 + r) * 8 + (c4 & 7);
    *reinterpret_cast<us4*>(op) = o;
}

// ---------------------------------------------------------------------------
// Kernel 6: MFMA attention, head-split + dbuf counted-vmcnt pipeline
// (round-18 proven, XCD swizzle reverted — measured null).
// ---------------------------------------------------------------------------
struct P4 { __bf16* p[4]; };

__global__ __launch_bounds__(512) void attn_mfma(const __bf16* __restrict__ q,
                                                 const __bf16* __restrict__ kw,
                                                 const __bf16* __restrict__ vt,
                                                 P4 ps) {
    __shared__ __align__(16) char smem[65536];
    int sgq = blockIdx.x;
    int b = blockIdx.y;
    int tp = blockIdx.z;
    int tid = threadIdx.x;
    int wid = tid >> 6;       // 0..7
    int lane = tid & 63;
    int lg = lane >> 4;
    int lr = lane & 15;
    int sgrp = wid & 1;       // s-group within block
    int hq = wid >> 1;        // head quarter 0..3
    int hbase = hq * 4;
    int s0 = (sgq * 2 + sgrp) * 16;

    const __bf16* qbase = q + ((size_t)(b * SS + s0 + lr)) * DD + lg * 8;
    const char* kwb8 = (const char*)kw + (size_t)b * SS * DD * 2;
    const char* vtb8 = (const char*)vt + (size_t)b * 128 * 8192;

    bf16x8 qf[4];
#pragma unroll
    for (int hi = 0; hi < 4; ++hi)
        qf[hi] = *reinterpret_cast<const bf16x8*>(qbase + (hbase + hi) * 32);

    f32x4 acc[4][2];
#pragma unroll
    for (int hi = 0; hi < 4; ++hi) {
        acc[hi][0] = (f32x4){0.f, 0.f, 0.f, 0.f};
        acc[hi][1] = (f32x4){0.f, 0.f, 0.f, 0.f};
    }

    // per-wave: 2 kw loads FIRST, then 2 vt loads (counted-wait order)
    auto stage = [&](int tbase, int bsel) {
#pragma unroll
        for (int i = 0; i < 2; ++i) {
            int row = wid + i * 8;
            int colb = (lane * 16) ^ ((row & 15) << 4);
            gload16(kwb8 + (size_t)(tbase + row) * 1024 + colb,
                    smem + bsel * 16384 + row * 1024);
        }
#pragma unroll
        for (int i = 0; i < 2; ++i) {
            int blkid = wid + i * 8;
            gload16(vtb8 + (size_t)((tbase >> 3) + (blkid >> 3)) * 8192 + (blkid & 7) * 1024 + lane * 16,
                    smem + 32768 + bsel * 16384 + blkid * 1024);
        }
    };

    int tbase0 = tp * 256;
    stage(tbase0, 0);

    for (int tc = 0; tc < 256; tc += 16) {
        int cur = (tc >> 4) & 1;
        char* kwbuf = smem + cur * 16384;
        char* vtbuf = smem + 32768 + cur * 16384;
        char* xch = kwbuf + sgrp * 4096;   // aliases kw rows 0..7 (free after QK)

        asm volatile("s_waitcnt vmcnt(2)" ::: "memory");
        __builtin_amdgcn_s_barrier();
        __builtin_amdgcn_sched_barrier(0);

        // ---- QK: own 4 heads; t = tbase + 4*lg + r, row = lr (identity)
        f32x4 sc[4];
        bf16x8 ka[4];
#pragma unroll
        for (int hi = 0; hi < 4; ++hi)
            ka[hi] = *reinterpret_cast<const bf16x8*>(
                kwbuf + lr * 1024 + ((((hbase + hi) * 64) + lg * 16) ^ (lr << 4)));
        __builtin_amdgcn_s_setprio(1);
#pragma unroll
        for (int hi = 0; hi < 4; ++hi) {
            f32x4 z = (f32x4){0.f, 0.f, 0.f, 0.f};
            sc[hi] = __builtin_amdgcn_mfma_f32_16x16x32_bf16(ka[hi], qf[hi], z, 0, 0, 0);
        }
        __builtin_amdgcn_s_setprio(0);

        __builtin_amdgcn_s_barrier();
        __builtin_amdgcn_sched_barrier(0);

        // ---- softmax: local exp + partial sum; overlap next-chunk stage
#pragma unroll
        for (int hi = 0; hi < 4; ++hi)
#pragma unroll
            for (int r = 0; r < 4; ++r) sc[hi][r] = exp2f(sc[hi][r]);
        f32x4 zsp = sc[0] + sc[1] + sc[2] + sc[3];
        *reinterpret_cast<f32x4*>(xch + hq * 1024 + lane * 16) = zsp;
        if (tc + 16 < 256) stage(tbase0 + tc + 16, cur ^ 1);
        asm volatile("s_waitcnt lgkmcnt(0)" ::: "memory");
        __builtin_amdgcn_s_barrier();
        __builtin_amdgcn_sched_barrier(0);

        f32x4 zt = zsp;
#pragma unroll
        for (int p = 0; p < 4; ++p)
            if (p != hq) zt += *reinterpret_cast<const f32x4*>(xch + p * 1024 + lane * 16);
        float inv[4];
#pragma unroll
        for (int r = 0; r < 4; ++r) inv[r] = __builtin_amdgcn_rcpf(zt[r]);
        bf16x4 pA[4];
#pragma unroll
        for (int hi = 0; hi < 4; ++hi)
#pragma unroll
            for (int r = 0; r < 4; ++r) pA[hi][r] = (__bf16)(sc[hi][r] * inv[r]);

        if (tc + 16 < 256) {
            asm volatile("s_waitcnt vmcnt(4)" ::: "memory");
        } else {
            asm volatile("s_waitcnt vmcnt(0)" ::: "memory");
        }
        __builtin_amdgcn_s_barrier();
        __builtin_amdgcn_sched_barrier(0);

        // ---- PV (K=16): vf = 4 consecutive t at tbase + 4*lg
        const char* vb = vtbuf + (lg >> 1) * 8192 + (lg & 1) * 8;
#pragma unroll
        for (int hi = 0; hi < 4; hi += 2) {
            s16x4 vf[4];
#pragma unroll
            for (int j = 0; j < 2; ++j) {
                int h = hbase + hi + j;
                vf[2 * j + 0] = *reinterpret_cast<const s16x4*>(vb + (h * 32 + lr) * 16);
                vf[2 * j + 1] = *reinterpret_cast<const s16x4*>(vb + (h * 32 + 16 + lr) * 16);
            }
            __builtin_amdgcn_s_setprio(1);
#pragma unroll
            for (int j = 0; j < 2; ++j) {
                s16x4 pa = __builtin_bit_cast(s16x4, pA[hi + j]);
                acc[hi + j][0] = __builtin_amdgcn_mfma_f32_16x16x16bf16_1k(pa, vf[2 * j + 0], acc[hi + j][0], 0, 0, 0);
                acc[hi + j][1] = __builtin_amdgcn_mfma_f32_16x16x16bf16_1k(pa, vf[2 * j + 1], acc[hi + j][1], 0, 0, 0);
            }
            __builtin_amdgcn_s_setprio(0);
        }
        // next iter's top vmcnt(2)+barrier protects buffer reuse
    }

    __bf16* pb = ps.p[tp] + ((size_t)(b * SS + s0)) * DD;
#pragma unroll
    for (int hi = 0; hi < 4; ++hi)
#pragma unroll
        for (int dh = 0; dh < 2; ++dh)
#pragma unroll
            for (int r = 0; r < 4; ++r)
                pb[(size_t)(lg * 4 + r) * DD + (hbase + hi) * 32 + dh * 16 + lr] = (__bf16)acc[hi][dh][r];
}

// ---------------------------------------------------------------------------
// Kernel 7: combine  comb = (sum of 4 partials)*mg + hf  -> bf16
// ---------------------------------------------------------------------------
struct P4c { const __bf16* p[4]; };

__global__ __launch_bounds__(256) void combine_kernel(P4c ps,
                                                      const __bf16* __restrict__ mg,
                                                      const __bf16* __restrict__ hf,
                                                      __bf16* __restrict__ comb) {
    size_t f = ((size_t)blockIdx.x * 256 + threadIdx.x) * 8;
    float accv[8] = {0.f, 0.f, 0.f, 0.f, 0.f, 0.f, 0.f, 0.f};
#pragma unroll
    for (int i = 0; i < 4; ++i) {
        bf16x8 v = *reinterpret_cast<const bf16x8*>(ps.p[i] + f);
#pragma unroll
        for (int j = 0; j < 8; ++j) accv[j] += (float)v[j];
    }
    bf16x8 m = *reinterpret_cast<const bf16x8*>(mg + f);
    bf16x8 hh = *reinterpret_cast<const bf16x8*>(hf + f);
    bf16x8 o;
#pragma unroll
    for (int j = 0; j < 8; ++j) o[j] = (__bf16)(accv[j] * (float)m[j] + (float)hh[j]);
    *reinterpret_cast<bf16x8*>(comb + f) = o;
}

// ---------------------------------------------------------------------------
extern "C" void kernel_launch(void* const* d_in, const int* in_sizes, int n_in,
                              void* d_out, int out_size, void* d_ws, size_t ws_size,
                              hipStream_t stream) {
    const float* x    = (const float*)d_in[0];
    const float* ln_g = (const float*)d_in[1];
    const float* ln_b = (const float*)d_in[2];
    const float* Wfa  = (const float*)d_in[3];  const float* bfa = (const float*)d_in[4];
    const float* Whp  = (const float*)d_in[5];  const float* bhp = (const float*)d_in[6];
    const float* Wmg  = (const float*)d_in[7];  const float* bmg = (const float*)d_in[8];
    const float* Wq   = (const float*)d_in[9];  const float* bq  = (const float*)d_in[10];
    const float* Wk   = (const float*)d_in[11]; const float* bk  = (const float*)d_in[12];
    const float* Wv   = (const float*)d_in[13]; const float* bv  = (const float*)d_in[14];
    const float* Wo   = (const float*)d_in[15]; const float* bo  = (const float*)d_in[16];
    float* out = (float*)d_out;

    char* w8 = (char*)d_ws;
    // Memory map (MB offsets). Every [B,S,D] bf16 tensor is 4 MB.
    __bf16* Wt   = (__bf16*)(w8 + ((size_t) 0 << 20)); // 3.5 MB used
    __bf16* xn   = (__bf16*)(w8 + ((size_t) 4 << 20)); // [4,8)   dead after 6-gemm
    __bf16* fa   = (__bf16*)(w8 + ((size_t) 8 << 20)); // [8,12)  dead after kweight
    __bf16* hf   = (__bf16*)(w8 + ((size_t)12 << 20)); // [12,16)
    __bf16* mg   = (__bf16*)(w8 + ((size_t)16 << 20)); // [16,20)
    __bf16* q    = (__bf16*)(w8 + ((size_t)20 << 20)); // [20,24)
    __bf16* k    = (__bf16*)(w8 + ((size_t)24 << 20)); // [24,28) dead after kweight
    __bf16* v    = (__bf16*)(w8 + ((size_t)28 << 20)); // [28,32) dead after vtrans
    __bf16* kw   = (__bf16*)(w8 + ((size_t)32 << 20)); // [32,36)
    __bf16* vt   = (__bf16*)(w8 + ((size_t)36 << 20)); // [36,40)
    // 4 bf16 partials (4 MB each): reuse dead xn/fa/k/v
    P4 ps;
    ps.p[0] = (__bf16*)(w8 + ((size_t) 4 << 20));
    ps.p[1] = (__bf16*)(w8 + ((size_t) 8 << 20));
    ps.p[2] = (__bf16*)(w8 + ((size_t)24 << 20));
    ps.p[3] = (__bf16*)(w8 + ((size_t)28 << 20));
    __bf16* comb = (__bf16*)(w8 + ((size_t)56 << 20)); // [56,60)
    float* pmax  = (float*) (w8 + ((size_t)60 << 20)); // stats ~80 KB
    float* psum  = pmax + 16 * DD;
    float2* smsc = (float2*)(psum + 16 * DD);

    // 1. LayerNorm -> xn bf16
    ln_kernel<<<NTOK, 256, 0, stream>>>(x, ln_g, ln_b, xn);

    // 2. Weight transpose+cast
    W7 wp; wp.p[0]=Wfa; wp.p[1]=Whp; wp.p[2]=Wmg; wp.p[3]=Wq; wp.p[4]=Wk; wp.p[5]=Wv; wp.p[6]=Wo;
    wprep<<<dim3(16, 16, 7), 256, 0, stream>>>(wp, Wt);

    // 3. FUSED 3-projection MFMA GEMM x 2 halves (A staged once per block)
    GemmCfg cfg;
    cfg.bias[0]=bfa; cfg.out[0]=fa; cfg.mode[0]=2;
    cfg.bias[1]=bhp; cfg.out[1]=hf; cfg.mode[1]=2;
    cfg.bias[2]=bmg; cfg.out[2]=mg; cfg.mode[2]=1;
    cfg.bias[3]=bq;  cfg.out[3]=q;  cfg.mode[3]=3;
    cfg.bias[4]=bk;  cfg.out[4]=k;  cfg.mode[4]=2;
    cfg.bias[5]=bv;  cfg.out[5]=v;  cfg.mode[5]=2;
    mfma_gemm3<<<dim3(32, 8, 2), 256, 0, stream>>>(xn, Wt, cfg);

    // 4. anchor softmax over sequence axis
    anchor_partial<<<dim3(8, 4, 4), dim3(64, 4), 0, stream>>>(fa, pmax, psum);
    anchor_merge<<<8, 256, 0, stream>>>(pmax, psum, smsc);
    kweight<<<1024, 256, 0, stream>>>(fa, k, smsc, kw);

    // 5. V transpose (tiled layout)
    vtrans<<<dim3(32, 16, 4), 256, 0, stream>>>(v, vt);

    // 6. MFMA attention -> 4 bf16 partials (pipelined head-split blocks)
    attn_mfma<<<dim3(32, 4, 4), 512, 0, stream>>>(q, kw, vt, ps);

    // 7. combine
    P4c pc;
    for (int i = 0; i < 4; ++i) pc.p[i] = ps.p[i];
    combine_kernel<<<1024, 256, 0, stream>>>(pc, mg, hf, comb);

    // 8. output projection + residual (128x64 dbuf GEMM)
    GemmCfg cfg2;
    for (int i = 0; i < 6; ++i) { cfg2.bias[i]=bo; cfg2.out[i]=out; cfg2.mode[i]=0; }
    mfma_gemm<<<dim3(32, 8, 1), 256, 0, stream>>>(comb, Wt + (size_t)6 * DD * DD, cfg2, x);
}